// Round 5
// baseline (20.445 us; speedup 1.0000x reference)
//
#include <hip/hip_runtime.h>
#include <cstddef>

#define EPSV 1e-8f

__device__ __forceinline__ float rdlane(float x, int s) {
    return __int_as_float(__builtin_amdgcn_readlane(__float_as_int(x), s));
}

#define GLD16(gp, lp) \
    __builtin_amdgcn_global_load_lds((const __attribute__((address_space(1))) void*)(gp), \
                                     (__attribute__((address_space(3))) void*)(lp), 16, 0, 0)

// Grid: 1024 blocks = 64 tiles(64 t-rows) x 16 l-pair-groups -> 4 blocks/CU,
// 16 waves/CU = 4 waves/SIMD. Block = 4 waves = 4 K-quarters (128 d each) of
// the same (64t x 2l) output group. NO barriers in the main loop: each wave
// streams its quarter through a wave-private double-buffered LDS sub-chunk
// (16 d), paced by counted s_waitcnt vmcnt(4). w2/h distributed in VGPRs,
// broadcast via v_readlane (statically-selected half regs, no runtime array
// indexing). One barrier total, for the 4-way K-combine.
// XCD: bid = lpg*64 + tile -> all 16 l-blocks of a tile share bid%8 = tile%8.
__global__ __launch_bounds__(256, 4) void fullmatch_kernel(
    const float* __restrict__ v1,       // [16,256,512]
    const float* __restrict__ v1_mask,  // [16,256]
    const float* __restrict__ v2,       // [16,512]
    const float* __restrict__ w,        // [32,512]
    float* __restrict__ out)            // [16,256,32]
{
    const int tid  = threadIdx.x;
    const int lane = tid & 63;
    const int wv   = tid >> 6;                          // K-quarter 0..3
    const int wvu  = __builtin_amdgcn_readfirstlane(wv);

    const int bid  = blockIdx.x;
    const int tile = bid & 63;
    const int lpg  = bid >> 6;                          // 0..15
    const int b    = tile >> 2;
    const int t0   = (tile & 3) * 64;
    const int p    = lpg;                               // l = p, p+16
    const int t    = t0 + lane;

    __shared__ float buf[4][2][64][16];   // 32 KB: per-wave double-buffered sub-chunk
    __shared__ float cmb[4][64][4];       // 4 KB: K-quarter combine

    const size_t rowbase = (size_t)(b * 256 + t0) * 512;
    const int    qoff    = wvu * 128;     // this wave's K-quarter (floats)

    // stage sub-chunk sc (16 d's of all 64 rows = 4 KB) into buffer half bs.
    // dest linear: lane l -> row i*16 + (l>>2), slot l&3 (16B slots).
    // read swizzle is quad j at slot j ^ ((row>>1)&3); since (row>>1)&3 =
    // (l>>3)&3 here, source pre-swizzle is m = (l&3) ^ ((l>>3)&3).
    #define STAGE(sc, bs)                                                          \
        do {                                                                       \
            _Pragma("unroll")                                                      \
            for (int i = 0; i < 4; ++i) {                                          \
                const int r = i * 16 + (lane >> 2);                                \
                const int m = (lane & 3) ^ ((lane >> 3) & 3);                      \
                GLD16(v1 + rowbase + (size_t)r * 512 + qoff + (sc) * 16 + m * 4,   \
                      &buf[wv][bs][i * 16][0]);                                    \
            }                                                                      \
        } while (0)

    STAGE(0, 0);   // issue first sub-chunk ASAP; HBM latency hides under prep

    // ---- w2/h distributed register slices (full D for n2) ----
    float4 w2A0, w2A1, w2B0, w2B1, hA0, hA1, hB0, hB1;
    float n2pA = 0.f, n2pB = 0.f;
    {
        const float* __restrict__ v2b = v2 + (size_t)b * 512;
        const float* __restrict__ wAp = w + (size_t)p * 512;
        const float* __restrict__ wBp = w + (size_t)(p + 16) * 512;
        {   // half 0: lane holds global quad `lane`
            const float4 wa = *(const float4*)(wAp + lane * 4);
            const float4 wb = *(const float4*)(wBp + lane * 4);
            const float4 vv = *(const float4*)(v2b + lane * 4);
            w2A0.x = wa.x*wa.x; w2A0.y = wa.y*wa.y; w2A0.z = wa.z*wa.z; w2A0.w = wa.w*wa.w;
            w2B0.x = wb.x*wb.x; w2B0.y = wb.y*wb.y; w2B0.z = wb.z*wb.z; w2B0.w = wb.w*wb.w;
            hA0.x = w2A0.x*vv.x; hA0.y = w2A0.y*vv.y; hA0.z = w2A0.z*vv.z; hA0.w = w2A0.w*vv.w;
            hB0.x = w2B0.x*vv.x; hB0.y = w2B0.y*vv.y; hB0.z = w2B0.z*vv.z; hB0.w = w2B0.w*vv.w;
            n2pA += hA0.x*vv.x + hA0.y*vv.y + hA0.z*vv.z + hA0.w*vv.w;
            n2pB += hB0.x*vv.x + hB0.y*vv.y + hB0.z*vv.z + hB0.w*vv.w;
        }
        {   // half 1: lane holds global quad 64+lane
            const float4 wa = *(const float4*)(wAp + 256 + lane * 4);
            const float4 wb = *(const float4*)(wBp + 256 + lane * 4);
            const float4 vv = *(const float4*)(v2b + 256 + lane * 4);
            w2A1.x = wa.x*wa.x; w2A1.y = wa.y*wa.y; w2A1.z = wa.z*wa.z; w2A1.w = wa.w*wa.w;
            w2B1.x = wb.x*wb.x; w2B1.y = wb.y*wb.y; w2B1.z = wb.z*wb.z; w2B1.w = wb.w*wb.w;
            hA1.x = w2A1.x*vv.x; hA1.y = w2A1.y*vv.y; hA1.z = w2A1.z*vv.z; hA1.w = w2A1.w*vv.w;
            hB1.x = w2B1.x*vv.x; hB1.y = w2B1.y*vv.y; hB1.z = w2B1.z*vv.z; hB1.w = w2B1.w*vv.w;
            n2pA += hA1.x*vv.x + hA1.y*vv.y + hA1.z*vv.z + hA1.w*vv.w;
            n2pB += hB1.x*vv.x + hB1.y*vv.y + hB1.z*vv.z + hB1.w*vv.w;
        }
    }
    // n2 butterfly only on the finalizing wave
    if (wvu == 0) {
        #pragma unroll
        for (int m = 32; m >= 1; m >>= 1) {
            n2pA += __shfl_xor(n2pA, m, 64);
            n2pB += __shfl_xor(n2pB, m, 64);
        }
    }

    // statically select this wave's half (no runtime-indexed register arrays)
    const int hi = wvu >> 1;
    const float4 sw2A = hi ? w2A1 : w2A0;
    const float4 sw2B = hi ? w2B1 : w2B0;
    const float4 shA  = hi ? hA1  : hA0;
    const float4 shB  = hi ? hB1  : hB0;
    const int libase  = (wvu & 1) << 5;   // lane base holding this quarter's quads

    float accNA = 0.f, accNB = 0.f, accDA = 0.f, accDB = 0.f;
    const int swz = (lane >> 1) & 3;

    #pragma unroll 2
    for (int sc = 0; sc < 8; ++sc) {
        if (sc < 7) {
            STAGE(sc + 1, (sc + 1) & 1);
            asm volatile("s_waitcnt vmcnt(4)" ::: "memory");  // sc's 4 loads done
        } else {
            asm volatile("s_waitcnt vmcnt(0)" ::: "memory");
        }
        const float* __restrict__ rowp = &buf[wv][sc & 1][lane][0];
        #pragma unroll
        for (int j = 0; j < 4; ++j) {
            const float4 a = *(const float4*)(rowp + ((j ^ swz) << 2));
            const int li = libase + sc * 4 + j;   // wave-uniform SGPR lane select

            const float wax = rdlane(sw2A.x, li);
            const float way = rdlane(sw2A.y, li);
            const float waz = rdlane(sw2A.z, li);
            const float waw = rdlane(sw2A.w, li);
            const float wbx = rdlane(sw2B.x, li);
            const float wby = rdlane(sw2B.y, li);
            const float wbz = rdlane(sw2B.z, li);
            const float wbw = rdlane(sw2B.w, li);
            const float hax = rdlane(shA.x, li);
            const float hay = rdlane(shA.y, li);
            const float haz = rdlane(shA.z, li);
            const float haw = rdlane(shA.w, li);
            const float hbx = rdlane(shB.x, li);
            const float hby = rdlane(shB.y, li);
            const float hbz = rdlane(shB.z, li);
            const float hbw = rdlane(shB.w, li);

            const float x2 = a.x * a.x, y2 = a.y * a.y;
            const float z2 = a.z * a.z, q2 = a.w * a.w;

            accNA = fmaf(a.x, hax, accNA);
            accNA = fmaf(a.y, hay, accNA);
            accNA = fmaf(a.z, haz, accNA);
            accNA = fmaf(a.w, haw, accNA);
            accNB = fmaf(a.x, hbx, accNB);
            accNB = fmaf(a.y, hby, accNB);
            accNB = fmaf(a.z, hbz, accNB);
            accNB = fmaf(a.w, hbw, accNB);
            accDA = fmaf(x2, wax, accDA);
            accDA = fmaf(y2, way, accDA);
            accDA = fmaf(z2, waz, accDA);
            accDA = fmaf(q2, waw, accDA);
            accDB = fmaf(x2, wbx, accDB);
            accDB = fmaf(y2, wby, accDB);
            accDB = fmaf(z2, wbz, accDB);
            accDB = fmaf(q2, wbw, accDB);
        }
    }

    // ---- combine the 4 K-quarters: single barrier ----
    cmb[wv][lane][0] = accNA;
    cmb[wv][lane][1] = accNB;
    cmb[wv][lane][2] = accDA;
    cmb[wv][lane][3] = accDB;
    __syncthreads();

    if (wvu == 0) {
        float nA = accNA, nB = accNB, dA = accDA, dB = accDB;
        #pragma unroll
        for (int q = 1; q < 4; ++q) {
            const float4 o = *(const float4*)(&cmb[q][lane][0]);
            nA += o.x; nB += o.y; dA += o.z; dB += o.w;
        }
        const float mk   = v1_mask[b * 256 + t];
        const float amk  = fabsf(mk);
        const float n2vA = sqrtf(n2pA);
        const float n2vB = sqrtf(n2pB);
        const float denA = fmaxf(sqrtf(dA) * amk * n2vA, EPSV);
        const float denB = fmaxf(sqrtf(dB) * amk * n2vB, EPSV);
        const size_t oix = (size_t)(b * 256 + t) * 32;
        out[oix + p]      = (nA * mk) / denA;
        out[oix + p + 16] = (nB * mk) / denB;
    }
    #undef STAGE
}

extern "C" void kernel_launch(void* const* d_in, const int* in_sizes, int n_in,
                              void* d_out, int out_size, void* d_ws, size_t ws_size,
                              hipStream_t stream) {
    const float* v1      = (const float*)d_in[0];
    const float* v1_mask = (const float*)d_in[1];
    const float* v2      = (const float*)d_in[2];
    const float* w       = (const float*)d_in[3];
    float* out           = (float*)d_out;

    fullmatch_kernel<<<dim3(1024), dim3(256), 0, stream>>>(v1, v1_mask, v2, w, out);
}